// Round 9
// baseline (249.748 us; speedup 1.0000x reference)
//
#include <hip/hip_runtime.h>
#include <hip/hip_fp16.h>

#define N_NODES 100000
#define N_EDGES 25000
#define K 128
#define NNZ 1600000

// edge buckets: 128 edges each; node buckets: 512 nodes each
#define NB_E 196   // ceil(25000/128)
#define NB_N 196   // ceil(100000/512)
#define SM_BLOCKS 25000   // softmax blocks (4 rows each) in fused kernel
// packed entry: (edge << 17) | node   (edge < 2^15, node < 2^17)

typedef float v2f __attribute__((ext_vector_type(2)));

// -------- fused: softmax (fp16 + fp8 out) | bucket histogram --------
__global__ __launch_bounds__(256) void sm_hist_k(const float* __restrict__ y,
                                                 __half2* __restrict__ probs_h,
                                                 unsigned short* __restrict__ probs8,
                                                 const int* __restrict__ ni,
                                                 const int* __restrict__ ei,
                                                 int* __restrict__ ebcnt,
                                                 int* __restrict__ nbcnt) {
    __shared__ int se[NB_E], sn[NB_N];
    if (blockIdx.x < SM_BLOCKS) {
        int wid = threadIdx.x >> 6, lane = threadIdx.x & 63;
        int row = blockIdx.x * 4 + wid;
        const float2* yr = (const float2*)(y + (size_t)row * K);
        float2 a = yr[lane];
        float m = fmaxf(a.x, a.y);
        #pragma unroll
        for (int off = 32; off >= 1; off >>= 1) m = fmaxf(m, __shfl_xor(m, off, 64));
        float e0 = expf(a.x - m);
        float e1 = expf(a.y - m);
        float s = e0 + e1;
        #pragma unroll
        for (int off = 32; off >= 1; off >>= 1) s += __shfl_xor(s, off, 64);
        float inv = 1.0f / s;
        float p0 = e0 * inv, p1 = e1 * inv;
        probs_h[(size_t)row * 64 + lane] = __floats2half2_rn(p0, p1);
        int pk = __builtin_amdgcn_cvt_pk_fp8_f32(p0, p1, 0, false);   // e4m3 (OCP on gfx950)
        probs8[(size_t)row * 64 + lane] = (unsigned short)(pk & 0xFFFF);
    } else {
        int bid = blockIdx.x - SM_BLOCKS;   // 0..1023
        for (int t = threadIdx.x; t < NB_E; t += 256) se[t] = 0;
        for (int t = threadIdx.x; t < NB_N; t += 256) sn[t] = 0;
        __syncthreads();
        for (int i = bid * 256 + threadIdx.x; i < NNZ; i += 1024 * 256) {
            atomicAdd(&se[ei[i] >> 7], 1);
            atomicAdd(&sn[ni[i] >> 9], 1);
        }
        __syncthreads();
        for (int t = threadIdx.x; t < NB_E; t += 256) if (se[t]) atomicAdd(&ebcnt[t], se[t]);
        for (int t = threadIdx.x; t < NB_N; t += 256) if (sn[t]) atomicAdd(&nbcnt[t], sn[t]);
    }
}

// ---------------- scan bucket counts -> offsets + cursors ----------------
__global__ __launch_bounds__(512) void bscan_k(const int* __restrict__ ebcnt,
                                               const int* __restrict__ nbcnt,
                                               int* __restrict__ ebOff, int* __restrict__ nbOff,
                                               int* __restrict__ ebCur, int* __restrict__ nbCur,
                                               int* __restrict__ e_off, int* __restrict__ n_off) {
    __shared__ int s[512];
    int t = threadIdx.x;
    int half = t >> 8, idx = t & 255;
    int v = 0;
    if (half == 0) v = (idx < NB_E) ? ebcnt[idx] : 0;
    else           v = (idx < NB_N) ? nbcnt[idx] : 0;
    s[t] = v;
    __syncthreads();
    for (int d = 1; d < 256; d <<= 1) {
        int add = (idx >= d) ? s[t - d] : 0;
        __syncthreads();
        s[t] += add;
        __syncthreads();
    }
    int excl = s[t] - v;
    if (half == 0 && idx < NB_E) {
        ebOff[idx] = excl; ebCur[idx] = excl;
        if (idx == NB_E - 1) ebOff[NB_E] = excl + v;
    }
    if (half == 1 && idx < NB_N) {
        nbOff[idx] = excl; nbCur[idx] = excl;
        if (idx == NB_N - 1) nbOff[NB_N] = excl + v;
    }
    if (t == 0) { e_off[N_EDGES] = NNZ; n_off[N_NODES] = NNZ; }
}

// ---------------- partition entries into buckets (both sides) ----------------
__global__ __launch_bounds__(256) void bpart_k(const int* __restrict__ ni,
                                               const int* __restrict__ ei,
                                               int* __restrict__ ebCur, int* __restrict__ nbCur,
                                               unsigned* __restrict__ ebkt,
                                               unsigned* __restrict__ nbkt) {
    __shared__ int cnt[NB_E > NB_N ? NB_E : NB_N];
    __shared__ int runb[NB_E > NB_N ? NB_E : NB_N];
    unsigned pk[8]; int rk[8]; bool val[8];
    int i0 = blockIdx.x * 2048;
    #pragma unroll
    for (int k = 0; k < 8; ++k) {
        int i = i0 + threadIdx.x + k * 256;
        val[k] = (i < NNZ);
        pk[k] = val[k] ? (((unsigned)ei[i] << 17) | (unsigned)ni[i]) : 0u;
    }
    // ---- edge side: bucket = pk >> 24 ----
    for (int t = threadIdx.x; t < NB_E; t += 256) cnt[t] = 0;
    __syncthreads();
    #pragma unroll
    for (int k = 0; k < 8; ++k) if (val[k]) rk[k] = atomicAdd(&cnt[pk[k] >> 24], 1);
    __syncthreads();
    for (int t = threadIdx.x; t < NB_E; t += 256)
        runb[t] = cnt[t] ? atomicAdd(&ebCur[t], cnt[t]) : 0;
    __syncthreads();
    #pragma unroll
    for (int k = 0; k < 8; ++k) if (val[k]) ebkt[runb[pk[k] >> 24] + rk[k]] = pk[k];
    __syncthreads();
    // ---- node side: bucket = (pk >> 9) & 0xFF ----
    for (int t = threadIdx.x; t < NB_N; t += 256) cnt[t] = 0;
    __syncthreads();
    #pragma unroll
    for (int k = 0; k < 8; ++k) if (val[k]) rk[k] = atomicAdd(&cnt[(pk[k] >> 9) & 0xFF], 1);
    __syncthreads();
    for (int t = threadIdx.x; t < NB_N; t += 256)
        runb[t] = cnt[t] ? atomicAdd(&nbCur[t], cnt[t]) : 0;
    __syncthreads();
    #pragma unroll
    for (int k = 0; k < 8; ++k) if (val[k]) nbkt[runb[(pk[k] >> 9) & 0xFF] + rk[k]] = pk[k];
}

// ------- per-bucket: counts -> local scan -> csr offsets + ranked fill -------
__global__ __launch_bounds__(256) void bfill_k(const unsigned* __restrict__ ebkt,
                                               const unsigned* __restrict__ nbkt,
                                               const int* __restrict__ ebOff,
                                               const int* __restrict__ nbOff,
                                               int* __restrict__ e_off, int* __restrict__ n_off,
                                               int* __restrict__ e_nodes,
                                               int* __restrict__ n_edges) {
    __shared__ int cnt[512];
    __shared__ int par[256];
    int b = blockIdx.x;
    int t = threadIdx.x;
    if (b < NB_E) {
        int beg = ebOff[b], end = ebOff[b + 1];
        for (int x = t; x < 128; x += 256) cnt[x] = 0;
        __syncthreads();
        int i = beg + t;
        for (; i + 768 < end; i += 1024) {
            unsigned p0 = ebkt[i], p1 = ebkt[i + 256], p2 = ebkt[i + 512], p3 = ebkt[i + 768];
            atomicAdd(&cnt[(p0 >> 17) & 127], 1);
            atomicAdd(&cnt[(p1 >> 17) & 127], 1);
            atomicAdd(&cnt[(p2 >> 17) & 127], 1);
            atomicAdd(&cnt[(p3 >> 17) & 127], 1);
        }
        for (; i < end; i += 256) atomicAdd(&cnt[(ebkt[i] >> 17) & 127], 1);
        __syncthreads();
        int v = (t < 128) ? cnt[t] : 0;
        par[t] = v;
        __syncthreads();
        for (int d = 1; d < 256; d <<= 1) {
            int add = (t >= d) ? par[t - d] : 0;
            __syncthreads();
            par[t] += add;
            __syncthreads();
        }
        if (t < 128) {
            int excl = par[t] - v;
            cnt[t] = excl;
            int e = (b << 7) + t;
            if (e < N_EDGES) e_off[e] = beg + excl;
        }
        __syncthreads();
        i = beg + t;
        for (; i + 768 < end; i += 1024) {
            unsigned p0 = ebkt[i], p1 = ebkt[i + 256], p2 = ebkt[i + 512], p3 = ebkt[i + 768];
            int d0 = atomicAdd(&cnt[(p0 >> 17) & 127], 1);
            int d1 = atomicAdd(&cnt[(p1 >> 17) & 127], 1);
            int d2 = atomicAdd(&cnt[(p2 >> 17) & 127], 1);
            int d3 = atomicAdd(&cnt[(p3 >> 17) & 127], 1);
            e_nodes[beg + d0] = p0 & 0x1FFFF;
            e_nodes[beg + d1] = p1 & 0x1FFFF;
            e_nodes[beg + d2] = p2 & 0x1FFFF;
            e_nodes[beg + d3] = p3 & 0x1FFFF;
        }
        for (; i < end; i += 256) {
            unsigned p = ebkt[i];
            int d = atomicAdd(&cnt[(p >> 17) & 127], 1);
            e_nodes[beg + d] = p & 0x1FFFF;
        }
    } else {
        int b2 = b - NB_E;
        int beg = nbOff[b2], end = nbOff[b2 + 1];
        for (int x = t; x < 512; x += 256) cnt[x] = 0;
        __syncthreads();
        int i = beg + t;
        for (; i + 768 < end; i += 1024) {
            unsigned p0 = nbkt[i], p1 = nbkt[i + 256], p2 = nbkt[i + 512], p3 = nbkt[i + 768];
            atomicAdd(&cnt[p0 & 511], 1);
            atomicAdd(&cnt[p1 & 511], 1);
            atomicAdd(&cnt[p2 & 511], 1);
            atomicAdd(&cnt[p3 & 511], 1);
        }
        for (; i < end; i += 256) atomicAdd(&cnt[nbkt[i] & 511], 1);
        __syncthreads();
        int v0 = cnt[t * 2], v1 = cnt[t * 2 + 1];
        int vs = v0 + v1;
        par[t] = vs;
        __syncthreads();
        for (int d = 1; d < 256; d <<= 1) {
            int add = (t >= d) ? par[t - d] : 0;
            __syncthreads();
            par[t] += add;
            __syncthreads();
        }
        int excl = par[t] - vs;
        __syncthreads();
        cnt[t * 2] = excl;
        cnt[t * 2 + 1] = excl + v0;
        int n = (b2 << 9) + t * 2;
        if (n < N_NODES)     n_off[n]     = beg + excl;
        if (n + 1 < N_NODES) n_off[n + 1] = beg + excl + v0;
        __syncthreads();
        i = beg + t;
        for (; i + 768 < end; i += 1024) {
            unsigned p0 = nbkt[i], p1 = nbkt[i + 256], p2 = nbkt[i + 512], p3 = nbkt[i + 768];
            int d0 = atomicAdd(&cnt[p0 & 511], 1);
            int d1 = atomicAdd(&cnt[p1 & 511], 1);
            int d2 = atomicAdd(&cnt[p2 & 511], 1);
            int d3 = atomicAdd(&cnt[p3 & 511], 1);
            n_edges[beg + d0] = p0 >> 17;
            n_edges[beg + d1] = p1 >> 17;
            n_edges[beg + d2] = p2 >> 17;
            n_edges[beg + d3] = p3 >> 17;
        }
        for (; i < end; i += 256) {
            unsigned p = nbkt[i];
            int d = atomicAdd(&cnt[p & 511], 1);
            n_edges[beg + d] = p >> 17;
        }
    }
}

// ------- fused: gather probs(fp8) -> edge mean -> @W -> edge_feat(fp16) -------
// 256 threads = 4 INDEPENDENT waves (no __syncthreads); each wave owns 2 edges.
// Within a wave: lanes 0-31 = edge A, lanes 32-63 = edge B; within an edge,
// 2 parity groups of 16 lanes stream entries beg+p, beg+p+2, ... 4-deep.
// Lane li (0..15) loads uint2 = 8 fp8 (cols li*8..+7). 16 rows in flight/wave.
__global__ __launch_bounds__(256) void mm2_k(const unsigned* __restrict__ probs8,
                                             const int* __restrict__ e_off,
                                             const int* __restrict__ e_nodes,
                                             const float* __restrict__ W,
                                             __half* __restrict__ edge_feat_h) {
    __shared__ float a_s[4][2][K];
    int wid = threadIdx.x >> 6, lane = threadIdx.x & 63;
    int eh = lane >> 5;            // which edge of the pair
    int p  = (lane >> 4) & 1;      // parity group within the edge
    int li = lane & 15;
    const uint2* pr2 = (const uint2*)probs8;      // 16 uint2 per 128B row

    int e = blockIdx.x * 8 + wid * 2 + eh;        // 3125*8 == 25000 exactly
    int beg = e_off[e], end = e_off[e + 1];
    float2 a0 = {0.f, 0.f}, a1 = {0.f, 0.f}, a2 = {0.f, 0.f}, a3 = {0.f, 0.f};
    int j = beg + p;
    // main loop: 4 independent idx->row chains per parity group
    for (; j + 6 < end; j += 8) {
        int i0 = e_nodes[j];
        int i1 = e_nodes[j + 2];
        int i2 = e_nodes[j + 4];
        int i3 = e_nodes[j + 6];
        uint2 q0 = pr2[(size_t)i0 * 16 + li];
        uint2 q1 = pr2[(size_t)i1 * 16 + li];
        uint2 q2 = pr2[(size_t)i2 * 16 + li];
        uint2 q3 = pr2[(size_t)i3 * 16 + li];
        v2f f;
        f = __builtin_amdgcn_cvt_pk_f32_fp8((int)q0.x, false); a0.x += f.x; a0.y += f.y;
        f = __builtin_amdgcn_cvt_pk_f32_fp8((int)q0.x, true);  a1.x += f.x; a1.y += f.y;
        f = __builtin_amdgcn_cvt_pk_f32_fp8((int)q0.y, false); a2.x += f.x; a2.y += f.y;
        f = __builtin_amdgcn_cvt_pk_f32_fp8((int)q0.y, true);  a3.x += f.x; a3.y += f.y;
        f = __builtin_amdgcn_cvt_pk_f32_fp8((int)q1.x, false); a0.x += f.x; a0.y += f.y;
        f = __builtin_amdgcn_cvt_pk_f32_fp8((int)q1.x, true);  a1.x += f.x; a1.y += f.y;
        f = __builtin_amdgcn_cvt_pk_f32_fp8((int)q1.y, false); a2.x += f.x; a2.y += f.y;
        f = __builtin_amdgcn_cvt_pk_f32_fp8((int)q1.y, true);  a3.x += f.x; a3.y += f.y;
        f = __builtin_amdgcn_cvt_pk_f32_fp8((int)q2.x, false); a0.x += f.x; a0.y += f.y;
        f = __builtin_amdgcn_cvt_pk_f32_fp8((int)q2.x, true);  a1.x += f.x; a1.y += f.y;
        f = __builtin_amdgcn_cvt_pk_f32_fp8((int)q2.y, false); a2.x += f.x; a2.y += f.y;
        f = __builtin_amdgcn_cvt_pk_f32_fp8((int)q2.y, true);  a3.x += f.x; a3.y += f.y;
        f = __builtin_amdgcn_cvt_pk_f32_fp8((int)q3.x, false); a0.x += f.x; a0.y += f.y;
        f = __builtin_amdgcn_cvt_pk_f32_fp8((int)q3.x, true);  a1.x += f.x; a1.y += f.y;
        f = __builtin_amdgcn_cvt_pk_f32_fp8((int)q3.y, false); a2.x += f.x; a2.y += f.y;
        f = __builtin_amdgcn_cvt_pk_f32_fp8((int)q3.y, true);  a3.x += f.x; a3.y += f.y;
    }
    for (; j < end; j += 2) {
        int idx = e_nodes[j];
        uint2 q = pr2[(size_t)idx * 16 + li];
        v2f f;
        f = __builtin_amdgcn_cvt_pk_f32_fp8((int)q.x, false); a0.x += f.x; a0.y += f.y;
        f = __builtin_amdgcn_cvt_pk_f32_fp8((int)q.x, true);  a1.x += f.x; a1.y += f.y;
        f = __builtin_amdgcn_cvt_pk_f32_fp8((int)q.y, false); a2.x += f.x; a2.y += f.y;
        f = __builtin_amdgcn_cvt_pk_f32_fp8((int)q.y, true);  a3.x += f.x; a3.y += f.y;
    }
    // combine the 2 parity groups (xor 16 stays within each 32-lane half)
    a0.x += __shfl_xor(a0.x, 16, 64); a0.y += __shfl_xor(a0.y, 16, 64);
    a1.x += __shfl_xor(a1.x, 16, 64); a1.y += __shfl_xor(a1.y, 16, 64);
    a2.x += __shfl_xor(a2.x, 16, 64); a2.y += __shfl_xor(a2.y, 16, 64);
    a3.x += __shfl_xor(a3.x, 16, 64); a3.y += __shfl_xor(a3.y, 16, 64);
    float inv = 1.0f / fmaxf((float)(end - beg), 1.0f);
    if (p == 0) {
        float* as = &a_s[wid][eh][li * 8];
        *(float4*)as       = make_float4(a0.x * inv, a0.y * inv, a1.x * inv, a1.y * inv);
        *(float4*)(as + 4) = make_float4(a2.x * inv, a2.y * inv, a3.x * inv, a3.y * inv);
    }
    // wave-internal LDS ordering (no cross-wave dependency -> no __syncthreads)
    asm volatile("s_waitcnt lgkmcnt(0)" ::: "memory");

    // GEMM: lane jp (0..63) computes both rows of its wave, cols jp*2, jp*2+1
    int jp = lane;
    float2 c0 = {0.f, 0.f}, c1 = {0.f, 0.f};
    for (int k = 0; k < K; k += 4) {
        float4 b0 = *(float4*)&a_s[wid][0][k];
        float4 b1 = *(float4*)&a_s[wid][1][k];
        float2 w0 = *(const float2*)&W[(k + 0) * K + jp * 2];
        float2 w1 = *(const float2*)&W[(k + 1) * K + jp * 2];
        float2 w2 = *(const float2*)&W[(k + 2) * K + jp * 2];
        float2 w3 = *(const float2*)&W[(k + 3) * K + jp * 2];
        c0.x += b0.x * w0.x + b0.y * w1.x + b0.z * w2.x + b0.w * w3.x;
        c0.y += b0.x * w0.y + b0.y * w1.y + b0.z * w2.y + b0.w * w3.y;
        c1.x += b1.x * w0.x + b1.y * w1.x + b1.z * w2.x + b1.w * w3.x;
        c1.y += b1.x * w0.y + b1.y * w1.y + b1.z * w2.y + b1.w * w3.y;
    }
    __half2* ef2 = (__half2*)edge_feat_h;
    int r0 = blockIdx.x * 8 + wid * 2;
    ef2[(size_t)(r0 + 0) * 64 + jp] = __floats2half2_rn(c0.x, c0.y);
    ef2[(size_t)(r0 + 1) * 64 + jp] = __floats2half2_rn(c1.x, c1.y);
}

// ------- fused: gather edge_feat(fp16, 4-deep MLP) -> node mean; nat-grad; mean-center -------
// 256 threads = 4 waves; block owns 16 nodes; wave owns 4 (lane-group g per node).
__global__ __launch_bounds__(256) void node_fin_k(const __half2* __restrict__ probs_h,
                                                  const int* __restrict__ n_off,
                                                  const int* __restrict__ n_edges,
                                                  const __half* __restrict__ edge_feat_h,
                                                  float* __restrict__ out) {
    int wid = threadIdx.x >> 6, lane = threadIdx.x & 63;
    int g = lane >> 4, li = lane & 15;
    int row = blockIdx.x * 16 + wid * 4 + g;      // 6250*16 == 100000 exactly
    int beg = n_off[row], end = n_off[row + 1];
    int deg = end - beg;

    const uint4* ef4 = (const uint4*)edge_feat_h;
    float2 a0 = {0.f, 0.f}, a1 = {0.f, 0.f}, a2 = {0.f, 0.f}, a3 = {0.f, 0.f};
    int t = beg;
    for (; t + 3 < end; t += 4) {
        int i0 = n_edges[t];
        int i1 = n_edges[t + 1];
        int i2 = n_edges[t + 2];
        int i3 = n_edges[t + 3];
        uint4 q0 = ef4[(size_t)i0 * 16 + li];
        uint4 q1 = ef4[(size_t)i1 * 16 + li];
        uint4 q2 = ef4[(size_t)i2 * 16 + li];
        uint4 q3 = ef4[(size_t)i3 * 16 + li];
        float2 f;
        f = __half22float2(*(__half2*)&q0.x); a0.x += f.x; a0.y += f.y;
        f = __half22float2(*(__half2*)&q0.y); a1.x += f.x; a1.y += f.y;
        f = __half22float2(*(__half2*)&q0.z); a2.x += f.x; a2.y += f.y;
        f = __half22float2(*(__half2*)&q0.w); a3.x += f.x; a3.y += f.y;
        f = __half22float2(*(__half2*)&q1.x); a0.x += f.x; a0.y += f.y;
        f = __half22float2(*(__half2*)&q1.y); a1.x += f.x; a1.y += f.y;
        f = __half22float2(*(__half2*)&q1.z); a2.x += f.x; a2.y += f.y;
        f = __half22float2(*(__half2*)&q1.w); a3.x += f.x; a3.y += f.y;
        f = __half22float2(*(__half2*)&q2.x); a0.x += f.x; a0.y += f.y;
        f = __half22float2(*(__half2*)&q2.y); a1.x += f.x; a1.y += f.y;
        f = __half22float2(*(__half2*)&q2.z); a2.x += f.x; a2.y += f.y;
        f = __half22float2(*(__half2*)&q2.w); a3.x += f.x; a3.y += f.y;
        f = __half22float2(*(__half2*)&q3.x); a0.x += f.x; a0.y += f.y;
        f = __half22float2(*(__half2*)&q3.y); a1.x += f.x; a1.y += f.y;
        f = __half22float2(*(__half2*)&q3.z); a2.x += f.x; a2.y += f.y;
        f = __half22float2(*(__half2*)&q3.w); a3.x += f.x; a3.y += f.y;
    }
    for (; t < end; ++t) {
        int idx = n_edges[t];
        uint4 q = ef4[(size_t)idx * 16 + li];
        float2 f;
        f = __half22float2(*(__half2*)&q.x); a0.x += f.x; a0.y += f.y;
        f = __half22float2(*(__half2*)&q.y); a1.x += f.x; a1.y += f.y;
        f = __half22float2(*(__half2*)&q.z); a2.x += f.x; a2.y += f.y;
        f = __half22float2(*(__half2*)&q.w); a3.x += f.x; a3.y += f.y;
    }
    float inv = 1.0f / fmaxf((float)deg, 1.0f);
    uint4 qp = ((const uint4*)probs_h)[(size_t)row * 16 + li];
    float2 p0 = __half22float2(*(__half2*)&qp.x);
    float2 p1 = __half22float2(*(__half2*)&qp.y);
    float2 p2 = __half22float2(*(__half2*)&qp.z);
    float2 p3 = __half22float2(*(__half2*)&qp.w);
    float v0 = fmaxf(p0.x, 1e-12f) * (a0.x * inv);
    float v1 = fmaxf(p0.y, 1e-12f) * (a0.y * inv);
    float v2 = fmaxf(p1.x, 1e-12f) * (a1.x * inv);
    float v3 = fmaxf(p1.y, 1e-12f) * (a1.y * inv);
    float v4 = fmaxf(p2.x, 1e-12f) * (a2.x * inv);
    float v5 = fmaxf(p2.y, 1e-12f) * (a2.y * inv);
    float v6 = fmaxf(p3.x, 1e-12f) * (a3.x * inv);
    float v7 = fmaxf(p3.y, 1e-12f) * (a3.y * inv);
    float s = ((v0 + v1) + (v2 + v3)) + ((v4 + v5) + (v6 + v7));
    #pragma unroll
    for (int off = 1; off <= 8; off <<= 1) s += __shfl_xor(s, off, 64);  // within 16-lane group
    float mean = s * (1.0f / (float)K);
    float* orow = out + (size_t)row * K + li * 8;
    *(float4*)orow       = make_float4(v0 - mean, v1 - mean, v2 - mean, v3 - mean);
    *(float4*)(orow + 4) = make_float4(v4 - mean, v5 - mean, v6 - mean, v7 - mean);
}

extern "C" void kernel_launch(void* const* d_in, const int* in_sizes, int n_in,
                              void* d_out, int out_size, void* d_ws, size_t ws_size,
                              hipStream_t stream) {
    const float* y        = (const float*)d_in[0];
    const float* W        = (const float*)d_in[1];
    const int*   node_idx = (const int*)d_in[2];
    const int*   edge_idx = (const int*)d_in[3];
    float* out = (float*)d_out;

    // workspace carve-up (4-byte units unless noted)
    unsigned* ebkt = (unsigned*)d_ws;                    // NNZ
    unsigned* nbkt = ebkt + NNZ;                         // NNZ
    int* e_nodes = (int*)(nbkt + NNZ);                   // NNZ
    int* n_edges = e_nodes + NNZ;                        // NNZ
    int* e_off   = n_edges + NNZ;                        // N_EDGES+1
    int* n_off   = e_off + (N_EDGES + 1);                // N_NODES+1
    int* ebcnt   = n_off + (N_NODES + 1);                // 200 (pad)
    int* nbcnt   = ebcnt + 200;                          // 200
    int* ebOff   = nbcnt + 200;                          // 200
    int* nbOff   = ebOff + 200;                          // 200
    int* ebCur   = nbOff + 200;                          // 200
    int* nbCur   = ebCur + 200;                          // 200
    uintptr_t pa = (uintptr_t)(nbCur + 200);
    pa = (pa + 255) & ~(uintptr_t)255;                   // 256B-align
    __half2* probs_h = (__half2*)pa;                     // N_NODES*64 half2 = 25.6 MB
    unsigned short* probs8 = (unsigned short*)(probs_h + (size_t)N_NODES * 64); // N_NODES*128 fp8 = 12.8 MB
    __half*  edge_feat_h = (__half*)ebkt;                // N_EDGES*K halves (6.4MB), aliases dead ebkt

    hipMemsetAsync(ebcnt, 0, 400 * sizeof(int), stream);

    sm_hist_k<<<SM_BLOCKS + 1024, 256, 0, stream>>>(y, probs_h, probs8,
                                                    node_idx, edge_idx, ebcnt, nbcnt);
    bscan_k<<<1, 512, 0, stream>>>(ebcnt, nbcnt, ebOff, nbOff, ebCur, nbCur, e_off, n_off);
    bpart_k<<<(NNZ + 2047) / 2048, 256, 0, stream>>>(node_idx, edge_idx, ebCur, nbCur, ebkt, nbkt);
    bfill_k<<<NB_E + NB_N, 256, 0, stream>>>(ebkt, nbkt, ebOff, nbOff, e_off, n_off, e_nodes, n_edges);

    mm2_k<<<N_EDGES / 8, 256, 0, stream>>>((const unsigned*)probs8, e_off, e_nodes, W, edge_feat_h);
    node_fin_k<<<N_NODES / 16, 256, 0, stream>>>(probs_h, n_off, n_edges, edge_feat_h, out);
}

// Round 11
// 233.267 us; speedup vs baseline: 1.0706x; 1.0706x over previous
//
#include <hip/hip_runtime.h>
#include <hip/hip_fp16.h>

#define N_NODES 100000
#define N_EDGES 25000
#define K 128
#define NNZ 1600000

// edge buckets: 128 edges each; node buckets: 512 nodes each
#define NB_E 196   // ceil(25000/128)
#define NB_N 196   // ceil(100000/512)
#define SM_BLOCKS 25000   // softmax blocks (4 rows each) in fused kernel
// packed entry: (edge << 17) | node   (edge < 2^15, node < 2^17)

typedef float v2f __attribute__((ext_vector_type(2)));

// -------- fused: softmax (fp16 + fp8 out) | bucket histogram --------
__global__ __launch_bounds__(256) void sm_hist_k(const float* __restrict__ y,
                                                 __half2* __restrict__ probs_h,
                                                 unsigned short* __restrict__ probs8,
                                                 const int* __restrict__ ni,
                                                 const int* __restrict__ ei,
                                                 int* __restrict__ ebcnt,
                                                 int* __restrict__ nbcnt) {
    __shared__ int se[NB_E], sn[NB_N];
    if (blockIdx.x < SM_BLOCKS) {
        int wid = threadIdx.x >> 6, lane = threadIdx.x & 63;
        int row = blockIdx.x * 4 + wid;
        const float2* yr = (const float2*)(y + (size_t)row * K);
        float2 a = yr[lane];
        float m = fmaxf(a.x, a.y);
        #pragma unroll
        for (int off = 32; off >= 1; off >>= 1) m = fmaxf(m, __shfl_xor(m, off, 64));
        float e0 = expf(a.x - m);
        float e1 = expf(a.y - m);
        float s = e0 + e1;
        #pragma unroll
        for (int off = 32; off >= 1; off >>= 1) s += __shfl_xor(s, off, 64);
        float inv = 1.0f / s;
        float p0 = e0 * inv, p1 = e1 * inv;
        probs_h[(size_t)row * 64 + lane] = __floats2half2_rn(p0, p1);
        int pk = __builtin_amdgcn_cvt_pk_fp8_f32(p0, p1, 0, false);   // e4m3 (OCP on gfx950)
        probs8[(size_t)row * 64 + lane] = (unsigned short)(pk & 0xFFFF);
    } else {
        int bid = blockIdx.x - SM_BLOCKS;   // 0..1023
        for (int t = threadIdx.x; t < NB_E; t += 256) se[t] = 0;
        for (int t = threadIdx.x; t < NB_N; t += 256) sn[t] = 0;
        __syncthreads();
        for (int i = bid * 256 + threadIdx.x; i < NNZ; i += 1024 * 256) {
            atomicAdd(&se[ei[i] >> 7], 1);
            atomicAdd(&sn[ni[i] >> 9], 1);
        }
        __syncthreads();
        for (int t = threadIdx.x; t < NB_E; t += 256) if (se[t]) atomicAdd(&ebcnt[t], se[t]);
        for (int t = threadIdx.x; t < NB_N; t += 256) if (sn[t]) atomicAdd(&nbcnt[t], sn[t]);
    }
}

// ---------------- scan bucket counts -> offsets + cursors ----------------
__global__ __launch_bounds__(512) void bscan_k(const int* __restrict__ ebcnt,
                                               const int* __restrict__ nbcnt,
                                               int* __restrict__ ebOff, int* __restrict__ nbOff,
                                               int* __restrict__ ebCur, int* __restrict__ nbCur,
                                               int* __restrict__ e_off, int* __restrict__ n_off) {
    __shared__ int s[512];
    int t = threadIdx.x;
    int half = t >> 8, idx = t & 255;
    int v = 0;
    if (half == 0) v = (idx < NB_E) ? ebcnt[idx] : 0;
    else           v = (idx < NB_N) ? nbcnt[idx] : 0;
    s[t] = v;
    __syncthreads();
    for (int d = 1; d < 256; d <<= 1) {
        int add = (idx >= d) ? s[t - d] : 0;
        __syncthreads();
        s[t] += add;
        __syncthreads();
    }
    int excl = s[t] - v;
    if (half == 0 && idx < NB_E) {
        ebOff[idx] = excl; ebCur[idx] = excl;
        if (idx == NB_E - 1) ebOff[NB_E] = excl + v;
    }
    if (half == 1 && idx < NB_N) {
        nbOff[idx] = excl; nbCur[idx] = excl;
        if (idx == NB_N - 1) nbOff[NB_N] = excl + v;
    }
    if (t == 0) { e_off[N_EDGES] = NNZ; n_off[N_NODES] = NNZ; }
}

// ---------------- partition entries into buckets (both sides) ----------------
__global__ __launch_bounds__(256) void bpart_k(const int* __restrict__ ni,
                                               const int* __restrict__ ei,
                                               int* __restrict__ ebCur, int* __restrict__ nbCur,
                                               unsigned* __restrict__ ebkt,
                                               unsigned* __restrict__ nbkt) {
    __shared__ int cnt[NB_E > NB_N ? NB_E : NB_N];
    __shared__ int runb[NB_E > NB_N ? NB_E : NB_N];
    unsigned pk[8]; int rk[8]; bool val[8];
    int i0 = blockIdx.x * 2048;
    #pragma unroll
    for (int k = 0; k < 8; ++k) {
        int i = i0 + threadIdx.x + k * 256;
        val[k] = (i < NNZ);
        pk[k] = val[k] ? (((unsigned)ei[i] << 17) | (unsigned)ni[i]) : 0u;
    }
    // ---- edge side: bucket = pk >> 24 ----
    for (int t = threadIdx.x; t < NB_E; t += 256) cnt[t] = 0;
    __syncthreads();
    #pragma unroll
    for (int k = 0; k < 8; ++k) if (val[k]) rk[k] = atomicAdd(&cnt[pk[k] >> 24], 1);
    __syncthreads();
    for (int t = threadIdx.x; t < NB_E; t += 256)
        runb[t] = cnt[t] ? atomicAdd(&ebCur[t], cnt[t]) : 0;
    __syncthreads();
    #pragma unroll
    for (int k = 0; k < 8; ++k) if (val[k]) ebkt[runb[pk[k] >> 24] + rk[k]] = pk[k];
    __syncthreads();
    // ---- node side: bucket = (pk >> 9) & 0xFF ----
    for (int t = threadIdx.x; t < NB_N; t += 256) cnt[t] = 0;
    __syncthreads();
    #pragma unroll
    for (int k = 0; k < 8; ++k) if (val[k]) rk[k] = atomicAdd(&cnt[(pk[k] >> 9) & 0xFF], 1);
    __syncthreads();
    for (int t = threadIdx.x; t < NB_N; t += 256)
        runb[t] = cnt[t] ? atomicAdd(&nbCur[t], cnt[t]) : 0;
    __syncthreads();
    #pragma unroll
    for (int k = 0; k < 8; ++k) if (val[k]) nbkt[runb[(pk[k] >> 9) & 0xFF] + rk[k]] = pk[k];
}

// ------- per-bucket: counts -> local scan -> csr offsets + ranked fill -------
__global__ __launch_bounds__(256) void bfill_k(const unsigned* __restrict__ ebkt,
                                               const unsigned* __restrict__ nbkt,
                                               const int* __restrict__ ebOff,
                                               const int* __restrict__ nbOff,
                                               int* __restrict__ e_off, int* __restrict__ n_off,
                                               int* __restrict__ e_nodes,
                                               int* __restrict__ n_edges) {
    __shared__ int cnt[512];
    __shared__ int par[256];
    int b = blockIdx.x;
    int t = threadIdx.x;
    if (b < NB_E) {
        int beg = ebOff[b], end = ebOff[b + 1];
        for (int x = t; x < 128; x += 256) cnt[x] = 0;
        __syncthreads();
        int i = beg + t;
        for (; i + 768 < end; i += 1024) {
            unsigned p0 = ebkt[i], p1 = ebkt[i + 256], p2 = ebkt[i + 512], p3 = ebkt[i + 768];
            atomicAdd(&cnt[(p0 >> 17) & 127], 1);
            atomicAdd(&cnt[(p1 >> 17) & 127], 1);
            atomicAdd(&cnt[(p2 >> 17) & 127], 1);
            atomicAdd(&cnt[(p3 >> 17) & 127], 1);
        }
        for (; i < end; i += 256) atomicAdd(&cnt[(ebkt[i] >> 17) & 127], 1);
        __syncthreads();
        int v = (t < 128) ? cnt[t] : 0;
        par[t] = v;
        __syncthreads();
        for (int d = 1; d < 256; d <<= 1) {
            int add = (t >= d) ? par[t - d] : 0;
            __syncthreads();
            par[t] += add;
            __syncthreads();
        }
        if (t < 128) {
            int excl = par[t] - v;
            cnt[t] = excl;
            int e = (b << 7) + t;
            if (e < N_EDGES) e_off[e] = beg + excl;
        }
        __syncthreads();
        i = beg + t;
        for (; i + 768 < end; i += 1024) {
            unsigned p0 = ebkt[i], p1 = ebkt[i + 256], p2 = ebkt[i + 512], p3 = ebkt[i + 768];
            int d0 = atomicAdd(&cnt[(p0 >> 17) & 127], 1);
            int d1 = atomicAdd(&cnt[(p1 >> 17) & 127], 1);
            int d2 = atomicAdd(&cnt[(p2 >> 17) & 127], 1);
            int d3 = atomicAdd(&cnt[(p3 >> 17) & 127], 1);
            e_nodes[beg + d0] = p0 & 0x1FFFF;
            e_nodes[beg + d1] = p1 & 0x1FFFF;
            e_nodes[beg + d2] = p2 & 0x1FFFF;
            e_nodes[beg + d3] = p3 & 0x1FFFF;
        }
        for (; i < end; i += 256) {
            unsigned p = ebkt[i];
            int d = atomicAdd(&cnt[(p >> 17) & 127], 1);
            e_nodes[beg + d] = p & 0x1FFFF;
        }
    } else {
        int b2 = b - NB_E;
        int beg = nbOff[b2], end = nbOff[b2 + 1];
        for (int x = t; x < 512; x += 256) cnt[x] = 0;
        __syncthreads();
        int i = beg + t;
        for (; i + 768 < end; i += 1024) {
            unsigned p0 = nbkt[i], p1 = nbkt[i + 256], p2 = nbkt[i + 512], p3 = nbkt[i + 768];
            atomicAdd(&cnt[p0 & 511], 1);
            atomicAdd(&cnt[p1 & 511], 1);
            atomicAdd(&cnt[p2 & 511], 1);
            atomicAdd(&cnt[p3 & 511], 1);
        }
        for (; i < end; i += 256) atomicAdd(&cnt[nbkt[i] & 511], 1);
        __syncthreads();
        int v0 = cnt[t * 2], v1 = cnt[t * 2 + 1];
        int vs = v0 + v1;
        par[t] = vs;
        __syncthreads();
        for (int d = 1; d < 256; d <<= 1) {
            int add = (t >= d) ? par[t - d] : 0;
            __syncthreads();
            par[t] += add;
            __syncthreads();
        }
        int excl = par[t] - vs;
        __syncthreads();
        cnt[t * 2] = excl;
        cnt[t * 2 + 1] = excl + v0;
        int n = (b2 << 9) + t * 2;
        if (n < N_NODES)     n_off[n]     = beg + excl;
        if (n + 1 < N_NODES) n_off[n + 1] = beg + excl + v0;
        __syncthreads();
        i = beg + t;
        for (; i + 768 < end; i += 1024) {
            unsigned p0 = nbkt[i], p1 = nbkt[i + 256], p2 = nbkt[i + 512], p3 = nbkt[i + 768];
            int d0 = atomicAdd(&cnt[p0 & 511], 1);
            int d1 = atomicAdd(&cnt[p1 & 511], 1);
            int d2 = atomicAdd(&cnt[p2 & 511], 1);
            int d3 = atomicAdd(&cnt[p3 & 511], 1);
            n_edges[beg + d0] = p0 >> 17;
            n_edges[beg + d1] = p1 >> 17;
            n_edges[beg + d2] = p2 >> 17;
            n_edges[beg + d3] = p3 >> 17;
        }
        for (; i < end; i += 256) {
            unsigned p = nbkt[i];
            int d = atomicAdd(&cnt[p & 511], 1);
            n_edges[beg + d] = p >> 17;
        }
    }
}

// ------- fused: gather probs(fp8, 16 lanes/row, 4-deep MLP) -> edge mean -> @W -> edge_feat(fp16) -------
// (round-7 structure: 4 waves/block, 16 edges/block, __syncthreads before GEMM)
__global__ __launch_bounds__(256) void mm2_k(const unsigned* __restrict__ probs8,
                                             const int* __restrict__ e_off,
                                             const int* __restrict__ e_nodes,
                                             const float* __restrict__ W,
                                             __half* __restrict__ edge_feat_h) {
    __shared__ float a_s[16][K];
    int wid = threadIdx.x >> 6, lane = threadIdx.x & 63;
    int g = lane >> 4, li = lane & 15;
    const uint2* pr2 = (const uint2*)probs8;      // 16 uint2 per 128B row

    for (int rr = 0; rr < 4; ++rr) {
        int e = blockIdx.x * 16 + wid * 4 + rr;
        int beg = 0, end = 0;
        if (e < N_EDGES) { beg = e_off[e]; end = e_off[e + 1]; }
        float2 a0 = {0.f, 0.f}, a1 = {0.f, 0.f}, a2 = {0.f, 0.f}, a3 = {0.f, 0.f};
        int j = beg + g;
        // main loop: 4 independent idx->row chains in flight per group
        for (; j + 12 < end; j += 16) {
            int i0 = e_nodes[j];
            int i1 = e_nodes[j + 4];
            int i2 = e_nodes[j + 8];
            int i3 = e_nodes[j + 12];
            uint2 q0 = pr2[(size_t)i0 * 16 + li];
            uint2 q1 = pr2[(size_t)i1 * 16 + li];
            uint2 q2 = pr2[(size_t)i2 * 16 + li];
            uint2 q3 = pr2[(size_t)i3 * 16 + li];
            v2f f;
            f = __builtin_amdgcn_cvt_pk_f32_fp8((int)q0.x, false); a0.x += f.x; a0.y += f.y;
            f = __builtin_amdgcn_cvt_pk_f32_fp8((int)q0.x, true);  a1.x += f.x; a1.y += f.y;
            f = __builtin_amdgcn_cvt_pk_f32_fp8((int)q0.y, false); a2.x += f.x; a2.y += f.y;
            f = __builtin_amdgcn_cvt_pk_f32_fp8((int)q0.y, true);  a3.x += f.x; a3.y += f.y;
            f = __builtin_amdgcn_cvt_pk_f32_fp8((int)q1.x, false); a0.x += f.x; a0.y += f.y;
            f = __builtin_amdgcn_cvt_pk_f32_fp8((int)q1.x, true);  a1.x += f.x; a1.y += f.y;
            f = __builtin_amdgcn_cvt_pk_f32_fp8((int)q1.y, false); a2.x += f.x; a2.y += f.y;
            f = __builtin_amdgcn_cvt_pk_f32_fp8((int)q1.y, true);  a3.x += f.x; a3.y += f.y;
            f = __builtin_amdgcn_cvt_pk_f32_fp8((int)q2.x, false); a0.x += f.x; a0.y += f.y;
            f = __builtin_amdgcn_cvt_pk_f32_fp8((int)q2.x, true);  a1.x += f.x; a1.y += f.y;
            f = __builtin_amdgcn_cvt_pk_f32_fp8((int)q2.y, false); a2.x += f.x; a2.y += f.y;
            f = __builtin_amdgcn_cvt_pk_f32_fp8((int)q2.y, true);  a3.x += f.x; a3.y += f.y;
            f = __builtin_amdgcn_cvt_pk_f32_fp8((int)q3.x, false); a0.x += f.x; a0.y += f.y;
            f = __builtin_amdgcn_cvt_pk_f32_fp8((int)q3.x, true);  a1.x += f.x; a1.y += f.y;
            f = __builtin_amdgcn_cvt_pk_f32_fp8((int)q3.y, false); a2.x += f.x; a2.y += f.y;
            f = __builtin_amdgcn_cvt_pk_f32_fp8((int)q3.y, true);  a3.x += f.x; a3.y += f.y;
        }
        for (; j < end; j += 4) {
            int idx = e_nodes[j];
            uint2 q = pr2[(size_t)idx * 16 + li];
            v2f f;
            f = __builtin_amdgcn_cvt_pk_f32_fp8((int)q.x, false); a0.x += f.x; a0.y += f.y;
            f = __builtin_amdgcn_cvt_pk_f32_fp8((int)q.x, true);  a1.x += f.x; a1.y += f.y;
            f = __builtin_amdgcn_cvt_pk_f32_fp8((int)q.y, false); a2.x += f.x; a2.y += f.y;
            f = __builtin_amdgcn_cvt_pk_f32_fp8((int)q.y, true);  a3.x += f.x; a3.y += f.y;
        }
        // combine the 4 lane-groups
        #pragma unroll
        for (int off = 16; off <= 32; off <<= 1) {
            a0.x += __shfl_xor(a0.x, off, 64); a0.y += __shfl_xor(a0.y, off, 64);
            a1.x += __shfl_xor(a1.x, off, 64); a1.y += __shfl_xor(a1.y, off, 64);
            a2.x += __shfl_xor(a2.x, off, 64); a2.y += __shfl_xor(a2.y, off, 64);
            a3.x += __shfl_xor(a3.x, off, 64); a3.y += __shfl_xor(a3.y, off, 64);
        }
        float inv = 1.0f / fmaxf((float)(end - beg), 1.0f);
        if (g == 0) {
            float* as = &a_s[wid * 4 + rr][li * 8];
            *(float4*)as       = make_float4(a0.x * inv, a0.y * inv, a1.x * inv, a1.y * inv);
            *(float4*)(as + 4) = make_float4(a2.x * inv, a2.y * inv, a3.x * inv, a3.y * inv);
        }
    }
    __syncthreads();

    // GEMM: thread (rq = tid>>6, jp = tid&63) computes rows rq*4..+3, cols jp*2,jp*2+1
    int rq = threadIdx.x >> 6;
    int jp = threadIdx.x & 63;
    float2 c0 = {0.f, 0.f}, c1 = {0.f, 0.f}, c2 = {0.f, 0.f}, c3 = {0.f, 0.f};
    for (int k = 0; k < K; k += 4) {
        float4 b0 = *(float4*)&a_s[rq * 4 + 0][k];
        float4 b1 = *(float4*)&a_s[rq * 4 + 1][k];
        float4 b2 = *(float4*)&a_s[rq * 4 + 2][k];
        float4 b3 = *(float4*)&a_s[rq * 4 + 3][k];
        float2 w0 = *(const float2*)&W[(k + 0) * K + jp * 2];
        float2 w1 = *(const float2*)&W[(k + 1) * K + jp * 2];
        float2 w2 = *(const float2*)&W[(k + 2) * K + jp * 2];
        float2 w3 = *(const float2*)&W[(k + 3) * K + jp * 2];
        c0.x += b0.x * w0.x + b0.y * w1.x + b0.z * w2.x + b0.w * w3.x;
        c0.y += b0.x * w0.y + b0.y * w1.y + b0.z * w2.y + b0.w * w3.y;
        c1.x += b1.x * w0.x + b1.y * w1.x + b1.z * w2.x + b1.w * w3.x;
        c1.y += b1.x * w0.y + b1.y * w1.y + b1.z * w2.y + b1.w * w3.y;
        c2.x += b2.x * w0.x + b2.y * w1.x + b2.z * w2.x + b2.w * w3.x;
        c2.y += b2.x * w0.y + b2.y * w1.y + b2.z * w2.y + b2.w * w3.y;
        c3.x += b3.x * w0.x + b3.y * w1.x + b3.z * w2.x + b3.w * w3.x;
        c3.y += b3.x * w0.y + b3.y * w1.y + b3.z * w2.y + b3.w * w3.y;
    }
    __half2* ef2 = (__half2*)edge_feat_h;
    int r0 = blockIdx.x * 16 + rq * 4;
    if (r0 + 0 < N_EDGES) ef2[(size_t)(r0 + 0) * 64 + jp] = __floats2half2_rn(c0.x, c0.y);
    if (r0 + 1 < N_EDGES) ef2[(size_t)(r0 + 1) * 64 + jp] = __floats2half2_rn(c1.x, c1.y);
    if (r0 + 2 < N_EDGES) ef2[(size_t)(r0 + 2) * 64 + jp] = __floats2half2_rn(c2.x, c2.y);
    if (r0 + 3 < N_EDGES) ef2[(size_t)(r0 + 3) * 64 + jp] = __floats2half2_rn(c3.x, c3.y);
}

// ------- fused: gather edge_feat(fp16, 4-deep MLP) -> node mean; nat-grad; mean-center -------
// 256 threads = 4 waves; block owns 16 nodes; wave owns 4 (lane-group g per node).
__global__ __launch_bounds__(256) void node_fin_k(const __half2* __restrict__ probs_h,
                                                  const int* __restrict__ n_off,
                                                  const int* __restrict__ n_edges,
                                                  const __half* __restrict__ edge_feat_h,
                                                  float* __restrict__ out) {
    int wid = threadIdx.x >> 6, lane = threadIdx.x & 63;
    int g = lane >> 4, li = lane & 15;
    int row = blockIdx.x * 16 + wid * 4 + g;      // 6250*16 == 100000 exactly
    int beg = n_off[row], end = n_off[row + 1];
    int deg = end - beg;

    const uint4* ef4 = (const uint4*)edge_feat_h;
    float2 a0 = {0.f, 0.f}, a1 = {0.f, 0.f}, a2 = {0.f, 0.f}, a3 = {0.f, 0.f};
    int t = beg;
    for (; t + 3 < end; t += 4) {
        int i0 = n_edges[t];
        int i1 = n_edges[t + 1];
        int i2 = n_edges[t + 2];
        int i3 = n_edges[t + 3];
        uint4 q0 = ef4[(size_t)i0 * 16 + li];
        uint4 q1 = ef4[(size_t)i1 * 16 + li];
        uint4 q2 = ef4[(size_t)i2 * 16 + li];
        uint4 q3 = ef4[(size_t)i3 * 16 + li];
        float2 f;
        f = __half22float2(*(__half2*)&q0.x); a0.x += f.x; a0.y += f.y;
        f = __half22float2(*(__half2*)&q0.y); a1.x += f.x; a1.y += f.y;
        f = __half22float2(*(__half2*)&q0.z); a2.x += f.x; a2.y += f.y;
        f = __half22float2(*(__half2*)&q0.w); a3.x += f.x; a3.y += f.y;
        f = __half22float2(*(__half2*)&q1.x); a0.x += f.x; a0.y += f.y;
        f = __half22float2(*(__half2*)&q1.y); a1.x += f.x; a1.y += f.y;
        f = __half22float2(*(__half2*)&q1.z); a2.x += f.x; a2.y += f.y;
        f = __half22float2(*(__half2*)&q1.w); a3.x += f.x; a3.y += f.y;
        f = __half22float2(*(__half2*)&q2.x); a0.x += f.x; a0.y += f.y;
        f = __half22float2(*(__half2*)&q2.y); a1.x += f.x; a1.y += f.y;
        f = __half22float2(*(__half2*)&q2.z); a2.x += f.x; a2.y += f.y;
        f = __half22float2(*(__half2*)&q2.w); a3.x += f.x; a3.y += f.y;
        f = __half22float2(*(__half2*)&q3.x); a0.x += f.x; a0.y += f.y;
        f = __half22float2(*(__half2*)&q3.y); a1.x += f.x; a1.y += f.y;
        f = __half22float2(*(__half2*)&q3.z); a2.x += f.x; a2.y += f.y;
        f = __half22float2(*(__half2*)&q3.w); a3.x += f.x; a3.y += f.y;
    }
    for (; t < end; ++t) {
        int idx = n_edges[t];
        uint4 q = ef4[(size_t)idx * 16 + li];
        float2 f;
        f = __half22float2(*(__half2*)&q.x); a0.x += f.x; a0.y += f.y;
        f = __half22float2(*(__half2*)&q.y); a1.x += f.x; a1.y += f.y;
        f = __half22float2(*(__half2*)&q.z); a2.x += f.x; a2.y += f.y;
        f = __half22float2(*(__half2*)&q.w); a3.x += f.x; a3.y += f.y;
    }
    float inv = 1.0f / fmaxf((float)deg, 1.0f);
    uint4 qp = ((const uint4*)probs_h)[(size_t)row * 16 + li];
    float2 p0 = __half22float2(*(__half2*)&qp.x);
    float2 p1 = __half22float2(*(__half2*)&qp.y);
    float2 p2 = __half22float2(*(__half2*)&qp.z);
    float2 p3 = __half22float2(*(__half2*)&qp.w);
    float v0 = fmaxf(p0.x, 1e-12f) * (a0.x * inv);
    float v1 = fmaxf(p0.y, 1e-12f) * (a0.y * inv);
    float v2 = fmaxf(p1.x, 1e-12f) * (a1.x * inv);
    float v3 = fmaxf(p1.y, 1e-12f) * (a1.y * inv);
    float v4 = fmaxf(p2.x, 1e-12f) * (a2.x * inv);
    float v5 = fmaxf(p2.y, 1e-12f) * (a2.y * inv);
    float v6 = fmaxf(p3.x, 1e-12f) * (a3.x * inv);
    float v7 = fmaxf(p3.y, 1e-12f) * (a3.y * inv);
    float s = ((v0 + v1) + (v2 + v3)) + ((v4 + v5) + (v6 + v7));
    #pragma unroll
    for (int off = 1; off <= 8; off <<= 1) s += __shfl_xor(s, off, 64);  // within 16-lane group
    float mean = s * (1.0f / (float)K);
    float* orow = out + (size_t)row * K + li * 8;
    *(float4*)orow       = make_float4(v0 - mean, v1 - mean, v2 - mean, v3 - mean);
    *(float4*)(orow + 4) = make_float4(v4 - mean, v5 - mean, v6 - mean, v7 - mean);
}

extern "C" void kernel_launch(void* const* d_in, const int* in_sizes, int n_in,
                              void* d_out, int out_size, void* d_ws, size_t ws_size,
                              hipStream_t stream) {
    const float* y        = (const float*)d_in[0];
    const float* W        = (const float*)d_in[1];
    const int*   node_idx = (const int*)d_in[2];
    const int*   edge_idx = (const int*)d_in[3];
    float* out = (float*)d_out;

    // workspace carve-up (4-byte units unless noted)
    unsigned* ebkt = (unsigned*)d_ws;                    // NNZ
    unsigned* nbkt = ebkt + NNZ;                         // NNZ
    int* e_nodes = (int*)(nbkt + NNZ);                   // NNZ
    int* n_edges = e_nodes + NNZ;                        // NNZ
    int* e_off   = n_edges + NNZ;                        // N_EDGES+1
    int* n_off   = e_off + (N_EDGES + 1);                // N_NODES+1
    int* ebcnt   = n_off + (N_NODES + 1);                // 200 (pad)
    int* nbcnt   = ebcnt + 200;                          // 200
    int* ebOff   = nbcnt + 200;                          // 200
    int* nbOff   = ebOff + 200;                          // 200
    int* ebCur   = nbOff + 200;                          // 200
    int* nbCur   = ebCur + 200;                          // 200
    uintptr_t pa = (uintptr_t)(nbCur + 200);
    pa = (pa + 255) & ~(uintptr_t)255;                   // 256B-align
    __half2* probs_h = (__half2*)pa;                     // N_NODES*64 half2 = 25.6 MB
    unsigned short* probs8 = (unsigned short*)(probs_h + (size_t)N_NODES * 64); // N_NODES*128 fp8 = 12.8 MB
    __half*  edge_feat_h = (__half*)ebkt;                // N_EDGES*K halves (6.4MB), aliases dead ebkt

    hipMemsetAsync(ebcnt, 0, 400 * sizeof(int), stream);

    sm_hist_k<<<SM_BLOCKS + 1024, 256, 0, stream>>>(y, probs_h, probs8,
                                                    node_idx, edge_idx, ebcnt, nbcnt);
    bscan_k<<<1, 512, 0, stream>>>(ebcnt, nbcnt, ebOff, nbOff, ebCur, nbCur, e_off, n_off);
    bpart_k<<<(NNZ + 2047) / 2048, 256, 0, stream>>>(node_idx, edge_idx, ebCur, nbCur, ebkt, nbkt);
    bfill_k<<<NB_E + NB_N, 256, 0, stream>>>(ebkt, nbkt, ebOff, nbOff, e_off, n_off, e_nodes, n_edges);

    mm2_k<<<(N_EDGES + 15) / 16, 256, 0, stream>>>((const unsigned*)probs8, e_off, e_nodes, W, edge_feat_h);
    node_fin_k<<<N_NODES / 16, 256, 0, stream>>>(probs_h, n_off, n_edges, edge_feat_h, out);
}

// Round 12
// 228.635 us; speedup vs baseline: 1.0923x; 1.0203x over previous
//
#include <hip/hip_runtime.h>
#include <hip/hip_fp16.h>

#define N_NODES 100000
#define N_EDGES 25000
#define K 128
#define NNZ 1600000

// edge buckets: 128 edges each; node buckets: 512 nodes each
#define NB_E 196   // ceil(25000/128)
#define NB_N 196   // ceil(100000/512)
#define SM_BLOCKS 6250   // softmax blocks (16 rows each) in fused kernel
// packed entry: (edge << 17) | node   (edge < 2^15, node < 2^17)

typedef float v2f __attribute__((ext_vector_type(2)));

// -------- fused: softmax (fp16 + fp8 out, 16 lanes/row) | bucket histogram --------
__global__ __launch_bounds__(256) void sm_hist_k(const float* __restrict__ y,
                                                 __half2* __restrict__ probs_h,
                                                 unsigned short* __restrict__ probs8,
                                                 const int* __restrict__ ni,
                                                 const int* __restrict__ ei,
                                                 int* __restrict__ ebcnt,
                                                 int* __restrict__ nbcnt) {
    __shared__ int se[NB_E], sn[NB_N];
    if (blockIdx.x < SM_BLOCKS) {
        int wid = threadIdx.x >> 6, lane = threadIdx.x & 63;
        int g = lane >> 4, li = lane & 15;
        int row = blockIdx.x * 16 + wid * 4 + g;   // 6250*16 == 100000 exactly
        const float4* y4 = (const float4*)(y + (size_t)row * K);
        float4 u = y4[li * 2];
        float4 v = y4[li * 2 + 1];                 // lane holds cols li*8 .. li*8+7
        float m = fmaxf(fmaxf(fmaxf(u.x, u.y), fmaxf(u.z, u.w)),
                        fmaxf(fmaxf(v.x, v.y), fmaxf(v.z, v.w)));
        #pragma unroll
        for (int off = 1; off <= 8; off <<= 1) m = fmaxf(m, __shfl_xor(m, off, 64));
        float e0 = expf(u.x - m), e1 = expf(u.y - m), e2 = expf(u.z - m), e3 = expf(u.w - m);
        float e4 = expf(v.x - m), e5 = expf(v.y - m), e6 = expf(v.z - m), e7 = expf(v.w - m);
        float s = ((e0 + e1) + (e2 + e3)) + ((e4 + e5) + (e6 + e7));
        #pragma unroll
        for (int off = 1; off <= 8; off <<= 1) s += __shfl_xor(s, off, 64);
        float inv = 1.0f / s;
        float p0 = e0 * inv, p1 = e1 * inv, p2 = e2 * inv, p3 = e3 * inv;
        float p4 = e4 * inv, p5 = e5 * inv, p6 = e6 * inv, p7 = e7 * inv;
        __half2 h0 = __floats2half2_rn(p0, p1), h1 = __floats2half2_rn(p2, p3);
        __half2 h2 = __floats2half2_rn(p4, p5), h3 = __floats2half2_rn(p6, p7);
        uint4 oh;
        oh.x = *(unsigned*)&h0; oh.y = *(unsigned*)&h1;
        oh.z = *(unsigned*)&h2; oh.w = *(unsigned*)&h3;
        ((uint4*)probs_h)[(size_t)row * 16 + li] = oh;
        int pkA = __builtin_amdgcn_cvt_pk_fp8_f32(p0, p1, 0, false);      // e4m3 (OCP)
        pkA     = __builtin_amdgcn_cvt_pk_fp8_f32(p2, p3, pkA, true);
        int pkB = __builtin_amdgcn_cvt_pk_fp8_f32(p4, p5, 0, false);
        pkB     = __builtin_amdgcn_cvt_pk_fp8_f32(p6, p7, pkB, true);
        uint2 o8 = make_uint2((unsigned)pkA, (unsigned)pkB);
        ((uint2*)probs8)[(size_t)row * 16 + li] = o8;
    } else {
        int bid = blockIdx.x - SM_BLOCKS;   // 0..1023
        for (int t = threadIdx.x; t < NB_E; t += 256) se[t] = 0;
        for (int t = threadIdx.x; t < NB_N; t += 256) sn[t] = 0;
        __syncthreads();
        for (int i = bid * 256 + threadIdx.x; i < NNZ; i += 1024 * 256) {
            atomicAdd(&se[ei[i] >> 7], 1);
            atomicAdd(&sn[ni[i] >> 9], 1);
        }
        __syncthreads();
        for (int t = threadIdx.x; t < NB_E; t += 256) if (se[t]) atomicAdd(&ebcnt[t], se[t]);
        for (int t = threadIdx.x; t < NB_N; t += 256) if (sn[t]) atomicAdd(&nbcnt[t], sn[t]);
    }
}

// ---------------- scan bucket counts -> offsets + cursors ----------------
__global__ __launch_bounds__(512) void bscan_k(const int* __restrict__ ebcnt,
                                               const int* __restrict__ nbcnt,
                                               int* __restrict__ ebOff, int* __restrict__ nbOff,
                                               int* __restrict__ ebCur, int* __restrict__ nbCur,
                                               int* __restrict__ e_off, int* __restrict__ n_off) {
    __shared__ int s[512];
    int t = threadIdx.x;
    int half = t >> 8, idx = t & 255;
    int v = 0;
    if (half == 0) v = (idx < NB_E) ? ebcnt[idx] : 0;
    else           v = (idx < NB_N) ? nbcnt[idx] : 0;
    s[t] = v;
    __syncthreads();
    for (int d = 1; d < 256; d <<= 1) {
        int add = (idx >= d) ? s[t - d] : 0;
        __syncthreads();
        s[t] += add;
        __syncthreads();
    }
    int excl = s[t] - v;
    if (half == 0 && idx < NB_E) {
        ebOff[idx] = excl; ebCur[idx] = excl;
        if (idx == NB_E - 1) ebOff[NB_E] = excl + v;
    }
    if (half == 1 && idx < NB_N) {
        nbOff[idx] = excl; nbCur[idx] = excl;
        if (idx == NB_N - 1) nbOff[NB_N] = excl + v;
    }
    if (t == 0) { e_off[N_EDGES] = NNZ; n_off[N_NODES] = NNZ; }
}

// ---------------- partition entries into buckets (both sides) ----------------
__global__ __launch_bounds__(256) void bpart_k(const int* __restrict__ ni,
                                               const int* __restrict__ ei,
                                               int* __restrict__ ebCur, int* __restrict__ nbCur,
                                               unsigned* __restrict__ ebkt,
                                               unsigned* __restrict__ nbkt) {
    __shared__ int cnt[NB_E > NB_N ? NB_E : NB_N];
    __shared__ int runb[NB_E > NB_N ? NB_E : NB_N];
    unsigned pk[8]; int rk[8]; bool val[8];
    int i0 = blockIdx.x * 2048;
    #pragma unroll
    for (int k = 0; k < 8; ++k) {
        int i = i0 + threadIdx.x + k * 256;
        val[k] = (i < NNZ);
        pk[k] = val[k] ? (((unsigned)ei[i] << 17) | (unsigned)ni[i]) : 0u;
    }
    // ---- edge side: bucket = pk >> 24 ----
    for (int t = threadIdx.x; t < NB_E; t += 256) cnt[t] = 0;
    __syncthreads();
    #pragma unroll
    for (int k = 0; k < 8; ++k) if (val[k]) rk[k] = atomicAdd(&cnt[pk[k] >> 24], 1);
    __syncthreads();
    for (int t = threadIdx.x; t < NB_E; t += 256)
        runb[t] = cnt[t] ? atomicAdd(&ebCur[t], cnt[t]) : 0;
    __syncthreads();
    #pragma unroll
    for (int k = 0; k < 8; ++k) if (val[k]) ebkt[runb[pk[k] >> 24] + rk[k]] = pk[k];
    __syncthreads();
    // ---- node side: bucket = (pk >> 9) & 0xFF ----
    for (int t = threadIdx.x; t < NB_N; t += 256) cnt[t] = 0;
    __syncthreads();
    #pragma unroll
    for (int k = 0; k < 8; ++k) if (val[k]) rk[k] = atomicAdd(&cnt[(pk[k] >> 9) & 0xFF], 1);
    __syncthreads();
    for (int t = threadIdx.x; t < NB_N; t += 256)
        runb[t] = cnt[t] ? atomicAdd(&nbCur[t], cnt[t]) : 0;
    __syncthreads();
    #pragma unroll
    for (int k = 0; k < 8; ++k) if (val[k]) nbkt[runb[(pk[k] >> 9) & 0xFF] + rk[k]] = pk[k];
}

// ------- per-bucket: counts -> local scan -> csr offsets + ranked fill -------
__global__ __launch_bounds__(256) void bfill_k(const unsigned* __restrict__ ebkt,
                                               const unsigned* __restrict__ nbkt,
                                               const int* __restrict__ ebOff,
                                               const int* __restrict__ nbOff,
                                               int* __restrict__ e_off, int* __restrict__ n_off,
                                               int* __restrict__ e_nodes,
                                               int* __restrict__ n_edges) {
    __shared__ int cnt[512];
    __shared__ int par[256];
    int b = blockIdx.x;
    int t = threadIdx.x;
    if (b < NB_E) {
        int beg = ebOff[b], end = ebOff[b + 1];
        for (int x = t; x < 128; x += 256) cnt[x] = 0;
        __syncthreads();
        int i = beg + t;
        for (; i + 768 < end; i += 1024) {
            unsigned p0 = ebkt[i], p1 = ebkt[i + 256], p2 = ebkt[i + 512], p3 = ebkt[i + 768];
            atomicAdd(&cnt[(p0 >> 17) & 127], 1);
            atomicAdd(&cnt[(p1 >> 17) & 127], 1);
            atomicAdd(&cnt[(p2 >> 17) & 127], 1);
            atomicAdd(&cnt[(p3 >> 17) & 127], 1);
        }
        for (; i < end; i += 256) atomicAdd(&cnt[(ebkt[i] >> 17) & 127], 1);
        __syncthreads();
        int v = (t < 128) ? cnt[t] : 0;
        par[t] = v;
        __syncthreads();
        for (int d = 1; d < 256; d <<= 1) {
            int add = (t >= d) ? par[t - d] : 0;
            __syncthreads();
            par[t] += add;
            __syncthreads();
        }
        if (t < 128) {
            int excl = par[t] - v;
            cnt[t] = excl;
            int e = (b << 7) + t;
            if (e < N_EDGES) e_off[e] = beg + excl;
        }
        __syncthreads();
        i = beg + t;
        for (; i + 768 < end; i += 1024) {
            unsigned p0 = ebkt[i], p1 = ebkt[i + 256], p2 = ebkt[i + 512], p3 = ebkt[i + 768];
            int d0 = atomicAdd(&cnt[(p0 >> 17) & 127], 1);
            int d1 = atomicAdd(&cnt[(p1 >> 17) & 127], 1);
            int d2 = atomicAdd(&cnt[(p2 >> 17) & 127], 1);
            int d3 = atomicAdd(&cnt[(p3 >> 17) & 127], 1);
            e_nodes[beg + d0] = p0 & 0x1FFFF;
            e_nodes[beg + d1] = p1 & 0x1FFFF;
            e_nodes[beg + d2] = p2 & 0x1FFFF;
            e_nodes[beg + d3] = p3 & 0x1FFFF;
        }
        for (; i < end; i += 256) {
            unsigned p = ebkt[i];
            int d = atomicAdd(&cnt[(p >> 17) & 127], 1);
            e_nodes[beg + d] = p & 0x1FFFF;
        }
    } else {
        int b2 = b - NB_E;
        int beg = nbOff[b2], end = nbOff[b2 + 1];
        for (int x = t; x < 512; x += 256) cnt[x] = 0;
        __syncthreads();
        int i = beg + t;
        for (; i + 768 < end; i += 1024) {
            unsigned p0 = nbkt[i], p1 = nbkt[i + 256], p2 = nbkt[i + 512], p3 = nbkt[i + 768];
            atomicAdd(&cnt[p0 & 511], 1);
            atomicAdd(&cnt[p1 & 511], 1);
            atomicAdd(&cnt[p2 & 511], 1);
            atomicAdd(&cnt[p3 & 511], 1);
        }
        for (; i < end; i += 256) atomicAdd(&cnt[nbkt[i] & 511], 1);
        __syncthreads();
        int v0 = cnt[t * 2], v1 = cnt[t * 2 + 1];
        int vs = v0 + v1;
        par[t] = vs;
        __syncthreads();
        for (int d = 1; d < 256; d <<= 1) {
            int add = (t >= d) ? par[t - d] : 0;
            __syncthreads();
            par[t] += add;
            __syncthreads();
        }
        int excl = par[t] - vs;
        __syncthreads();
        cnt[t * 2] = excl;
        cnt[t * 2 + 1] = excl + v0;
        int n = (b2 << 9) + t * 2;
        if (n < N_NODES)     n_off[n]     = beg + excl;
        if (n + 1 < N_NODES) n_off[n + 1] = beg + excl + v0;
        __syncthreads();
        i = beg + t;
        for (; i + 768 < end; i += 1024) {
            unsigned p0 = nbkt[i], p1 = nbkt[i + 256], p2 = nbkt[i + 512], p3 = nbkt[i + 768];
            int d0 = atomicAdd(&cnt[p0 & 511], 1);
            int d1 = atomicAdd(&cnt[p1 & 511], 1);
            int d2 = atomicAdd(&cnt[p2 & 511], 1);
            int d3 = atomicAdd(&cnt[p3 & 511], 1);
            n_edges[beg + d0] = p0 >> 17;
            n_edges[beg + d1] = p1 >> 17;
            n_edges[beg + d2] = p2 >> 17;
            n_edges[beg + d3] = p3 >> 17;
        }
        for (; i < end; i += 256) {
            unsigned p = nbkt[i];
            int d = atomicAdd(&cnt[p & 511], 1);
            n_edges[beg + d] = p >> 17;
        }
    }
}

// ------- fused: gather probs(fp8, 16 lanes/row, 4-deep MLP) -> edge mean -> @W -> edge_feat(fp16) -------
// (round-7 structure: 4 waves/block, 16 edges/block, __syncthreads before GEMM)
__global__ __launch_bounds__(256) void mm2_k(const unsigned* __restrict__ probs8,
                                             const int* __restrict__ e_off,
                                             const int* __restrict__ e_nodes,
                                             const float* __restrict__ W,
                                             __half* __restrict__ edge_feat_h) {
    __shared__ float a_s[16][K];
    int wid = threadIdx.x >> 6, lane = threadIdx.x & 63;
    int g = lane >> 4, li = lane & 15;
    const uint2* pr2 = (const uint2*)probs8;      // 16 uint2 per 128B row

    for (int rr = 0; rr < 4; ++rr) {
        int e = blockIdx.x * 16 + wid * 4 + rr;
        int beg = 0, end = 0;
        if (e < N_EDGES) { beg = e_off[e]; end = e_off[e + 1]; }
        float2 a0 = {0.f, 0.f}, a1 = {0.f, 0.f}, a2 = {0.f, 0.f}, a3 = {0.f, 0.f};
        int j = beg + g;
        // main loop: 4 independent idx->row chains in flight per group
        for (; j + 12 < end; j += 16) {
            int i0 = e_nodes[j];
            int i1 = e_nodes[j + 4];
            int i2 = e_nodes[j + 8];
            int i3 = e_nodes[j + 12];
            uint2 q0 = pr2[(size_t)i0 * 16 + li];
            uint2 q1 = pr2[(size_t)i1 * 16 + li];
            uint2 q2 = pr2[(size_t)i2 * 16 + li];
            uint2 q3 = pr2[(size_t)i3 * 16 + li];
            v2f f;
            f = __builtin_amdgcn_cvt_pk_f32_fp8((int)q0.x, false); a0.x += f.x; a0.y += f.y;
            f = __builtin_amdgcn_cvt_pk_f32_fp8((int)q0.x, true);  a1.x += f.x; a1.y += f.y;
            f = __builtin_amdgcn_cvt_pk_f32_fp8((int)q0.y, false); a2.x += f.x; a2.y += f.y;
            f = __builtin_amdgcn_cvt_pk_f32_fp8((int)q0.y, true);  a3.x += f.x; a3.y += f.y;
            f = __builtin_amdgcn_cvt_pk_f32_fp8((int)q1.x, false); a0.x += f.x; a0.y += f.y;
            f = __builtin_amdgcn_cvt_pk_f32_fp8((int)q1.x, true);  a1.x += f.x; a1.y += f.y;
            f = __builtin_amdgcn_cvt_pk_f32_fp8((int)q1.y, false); a2.x += f.x; a2.y += f.y;
            f = __builtin_amdgcn_cvt_pk_f32_fp8((int)q1.y, true);  a3.x += f.x; a3.y += f.y;
            f = __builtin_amdgcn_cvt_pk_f32_fp8((int)q2.x, false); a0.x += f.x; a0.y += f.y;
            f = __builtin_amdgcn_cvt_pk_f32_fp8((int)q2.x, true);  a1.x += f.x; a1.y += f.y;
            f = __builtin_amdgcn_cvt_pk_f32_fp8((int)q2.y, false); a2.x += f.x; a2.y += f.y;
            f = __builtin_amdgcn_cvt_pk_f32_fp8((int)q2.y, true);  a3.x += f.x; a3.y += f.y;
            f = __builtin_amdgcn_cvt_pk_f32_fp8((int)q3.x, false); a0.x += f.x; a0.y += f.y;
            f = __builtin_amdgcn_cvt_pk_f32_fp8((int)q3.x, true);  a1.x += f.x; a1.y += f.y;
            f = __builtin_amdgcn_cvt_pk_f32_fp8((int)q3.y, false); a2.x += f.x; a2.y += f.y;
            f = __builtin_amdgcn_cvt_pk_f32_fp8((int)q3.y, true);  a3.x += f.x; a3.y += f.y;
        }
        for (; j < end; j += 4) {
            int idx = e_nodes[j];
            uint2 q = pr2[(size_t)idx * 16 + li];
            v2f f;
            f = __builtin_amdgcn_cvt_pk_f32_fp8((int)q.x, false); a0.x += f.x; a0.y += f.y;
            f = __builtin_amdgcn_cvt_pk_f32_fp8((int)q.x, true);  a1.x += f.x; a1.y += f.y;
            f = __builtin_amdgcn_cvt_pk_f32_fp8((int)q.y, false); a2.x += f.x; a2.y += f.y;
            f = __builtin_amdgcn_cvt_pk_f32_fp8((int)q.y, true);  a3.x += f.x; a3.y += f.y;
        }
        // combine the 4 lane-groups
        #pragma unroll
        for (int off = 16; off <= 32; off <<= 1) {
            a0.x += __shfl_xor(a0.x, off, 64); a0.y += __shfl_xor(a0.y, off, 64);
            a1.x += __shfl_xor(a1.x, off, 64); a1.y += __shfl_xor(a1.y, off, 64);
            a2.x += __shfl_xor(a2.x, off, 64); a2.y += __shfl_xor(a2.y, off, 64);
            a3.x += __shfl_xor(a3.x, off, 64); a3.y += __shfl_xor(a3.y, off, 64);
        }
        float inv = 1.0f / fmaxf((float)(end - beg), 1.0f);
        if (g == 0) {
            float* as = &a_s[wid * 4 + rr][li * 8];
            *(float4*)as       = make_float4(a0.x * inv, a0.y * inv, a1.x * inv, a1.y * inv);
            *(float4*)(as + 4) = make_float4(a2.x * inv, a2.y * inv, a3.x * inv, a3.y * inv);
        }
    }
    __syncthreads();

    // GEMM: thread (rq = tid>>6, jp = tid&63) computes rows rq*4..+3, cols jp*2,jp*2+1
    int rq = threadIdx.x >> 6;
    int jp = threadIdx.x & 63;
    float2 c0 = {0.f, 0.f}, c1 = {0.f, 0.f}, c2 = {0.f, 0.f}, c3 = {0.f, 0.f};
    for (int k = 0; k < K; k += 4) {
        float4 b0 = *(float4*)&a_s[rq * 4 + 0][k];
        float4 b1 = *(float4*)&a_s[rq * 4 + 1][k];
        float4 b2 = *(float4*)&a_s[rq * 4 + 2][k];
        float4 b3 = *(float4*)&a_s[rq * 4 + 3][k];
        float2 w0 = *(const float2*)&W[(k + 0) * K + jp * 2];
        float2 w1 = *(const float2*)&W[(k + 1) * K + jp * 2];
        float2 w2 = *(const float2*)&W[(k + 2) * K + jp * 2];
        float2 w3 = *(const float2*)&W[(k + 3) * K + jp * 2];
        c0.x += b0.x * w0.x + b0.y * w1.x + b0.z * w2.x + b0.w * w3.x;
        c0.y += b0.x * w0.y + b0.y * w1.y + b0.z * w2.y + b0.w * w3.y;
        c1.x += b1.x * w0.x + b1.y * w1.x + b1.z * w2.x + b1.w * w3.x;
        c1.y += b1.x * w0.y + b1.y * w1.y + b1.z * w2.y + b1.w * w3.y;
        c2.x += b2.x * w0.x + b2.y * w1.x + b2.z * w2.x + b2.w * w3.x;
        c2.y += b2.x * w0.y + b2.y * w1.y + b2.z * w2.y + b2.w * w3.y;
        c3.x += b3.x * w0.x + b3.y * w1.x + b3.z * w2.x + b3.w * w3.x;
        c3.y += b3.x * w0.y + b3.y * w1.y + b3.z * w2.y + b3.w * w3.y;
    }
    __half2* ef2 = (__half2*)edge_feat_h;
    int r0 = blockIdx.x * 16 + rq * 4;
    if (r0 + 0 < N_EDGES) ef2[(size_t)(r0 + 0) * 64 + jp] = __floats2half2_rn(c0.x, c0.y);
    if (r0 + 1 < N_EDGES) ef2[(size_t)(r0 + 1) * 64 + jp] = __floats2half2_rn(c1.x, c1.y);
    if (r0 + 2 < N_EDGES) ef2[(size_t)(r0 + 2) * 64 + jp] = __floats2half2_rn(c2.x, c2.y);
    if (r0 + 3 < N_EDGES) ef2[(size_t)(r0 + 3) * 64 + jp] = __floats2half2_rn(c3.x, c3.y);
}

// ------- fused: gather edge_feat(fp16, 4-deep MLP) -> node mean; nat-grad; mean-center -------
// 256 threads = 4 waves; block owns 16 nodes; wave owns 4 (lane-group g per node).
__global__ __launch_bounds__(256) void node_fin_k(const __half2* __restrict__ probs_h,
                                                  const int* __restrict__ n_off,
                                                  const int* __restrict__ n_edges,
                                                  const __half* __restrict__ edge_feat_h,
                                                  float* __restrict__ out) {
    int wid = threadIdx.x >> 6, lane = threadIdx.x & 63;
    int g = lane >> 4, li = lane & 15;
    int row = blockIdx.x * 16 + wid * 4 + g;      // 6250*16 == 100000 exactly
    int beg = n_off[row], end = n_off[row + 1];
    int deg = end - beg;

    const uint4* ef4 = (const uint4*)edge_feat_h;
    float2 a0 = {0.f, 0.f}, a1 = {0.f, 0.f}, a2 = {0.f, 0.f}, a3 = {0.f, 0.f};
    int t = beg;
    for (; t + 3 < end; t += 4) {
        int i0 = n_edges[t];
        int i1 = n_edges[t + 1];
        int i2 = n_edges[t + 2];
        int i3 = n_edges[t + 3];
        uint4 q0 = ef4[(size_t)i0 * 16 + li];
        uint4 q1 = ef4[(size_t)i1 * 16 + li];
        uint4 q2 = ef4[(size_t)i2 * 16 + li];
        uint4 q3 = ef4[(size_t)i3 * 16 + li];
        float2 f;
        f = __half22float2(*(__half2*)&q0.x); a0.x += f.x; a0.y += f.y;
        f = __half22float2(*(__half2*)&q0.y); a1.x += f.x; a1.y += f.y;
        f = __half22float2(*(__half2*)&q0.z); a2.x += f.x; a2.y += f.y;
        f = __half22float2(*(__half2*)&q0.w); a3.x += f.x; a3.y += f.y;
        f = __half22float2(*(__half2*)&q1.x); a0.x += f.x; a0.y += f.y;
        f = __half22float2(*(__half2*)&q1.y); a1.x += f.x; a1.y += f.y;
        f = __half22float2(*(__half2*)&q1.z); a2.x += f.x; a2.y += f.y;
        f = __half22float2(*(__half2*)&q1.w); a3.x += f.x; a3.y += f.y;
        f = __half22float2(*(__half2*)&q2.x); a0.x += f.x; a0.y += f.y;
        f = __half22float2(*(__half2*)&q2.y); a1.x += f.x; a1.y += f.y;
        f = __half22float2(*(__half2*)&q2.z); a2.x += f.x; a2.y += f.y;
        f = __half22float2(*(__half2*)&q2.w); a3.x += f.x; a3.y += f.y;
        f = __half22float2(*(__half2*)&q3.x); a0.x += f.x; a0.y += f.y;
        f = __half22float2(*(__half2*)&q3.y); a1.x += f.x; a1.y += f.y;
        f = __half22float2(*(__half2*)&q3.z); a2.x += f.x; a2.y += f.y;
        f = __half22float2(*(__half2*)&q3.w); a3.x += f.x; a3.y += f.y;
    }
    for (; t < end; ++t) {
        int idx = n_edges[t];
        uint4 q = ef4[(size_t)idx * 16 + li];
        float2 f;
        f = __half22float2(*(__half2*)&q.x); a0.x += f.x; a0.y += f.y;
        f = __half22float2(*(__half2*)&q.y); a1.x += f.x; a1.y += f.y;
        f = __half22float2(*(__half2*)&q.z); a2.x += f.x; a2.y += f.y;
        f = __half22float2(*(__half2*)&q.w); a3.x += f.x; a3.y += f.y;
    }
    float inv = 1.0f / fmaxf((float)deg, 1.0f);
    uint4 qp = ((const uint4*)probs_h)[(size_t)row * 16 + li];
    float2 p0 = __half22float2(*(__half2*)&qp.x);
    float2 p1 = __half22float2(*(__half2*)&qp.y);
    float2 p2 = __half22float2(*(__half2*)&qp.z);
    float2 p3 = __half22float2(*(__half2*)&qp.w);
    float v0 = fmaxf(p0.x, 1e-12f) * (a0.x * inv);
    float v1 = fmaxf(p0.y, 1e-12f) * (a0.y * inv);
    float v2 = fmaxf(p1.x, 1e-12f) * (a1.x * inv);
    float v3 = fmaxf(p1.y, 1e-12f) * (a1.y * inv);
    float v4 = fmaxf(p2.x, 1e-12f) * (a2.x * inv);
    float v5 = fmaxf(p2.y, 1e-12f) * (a2.y * inv);
    float v6 = fmaxf(p3.x, 1e-12f) * (a3.x * inv);
    float v7 = fmaxf(p3.y, 1e-12f) * (a3.y * inv);
    float s = ((v0 + v1) + (v2 + v3)) + ((v4 + v5) + (v6 + v7));
    #pragma unroll
    for (int off = 1; off <= 8; off <<= 1) s += __shfl_xor(s, off, 64);  // within 16-lane group
    float mean = s * (1.0f / (float)K);
    float* orow = out + (size_t)row * K + li * 8;
    *(float4*)orow       = make_float4(v0 - mean, v1 - mean, v2 - mean, v3 - mean);
    *(float4*)(orow + 4) = make_float4(v4 - mean, v5 - mean, v6 - mean, v7 - mean);
}

extern "C" void kernel_launch(void* const* d_in, const int* in_sizes, int n_in,
                              void* d_out, int out_size, void* d_ws, size_t ws_size,
                              hipStream_t stream) {
    const float* y        = (const float*)d_in[0];
    const float* W        = (const float*)d_in[1];
    const int*   node_idx = (const int*)d_in[2];
    const int*   edge_idx = (const int*)d_in[3];
    float* out = (float*)d_out;

    // workspace carve-up (4-byte units unless noted)
    unsigned* ebkt = (unsigned*)d_ws;                    // NNZ
    unsigned* nbkt = ebkt + NNZ;                         // NNZ
    int* e_nodes = (int*)(nbkt + NNZ);                   // NNZ
    int* n_edges = e_nodes + NNZ;                        // NNZ
    int* e_off   = n_edges + NNZ;                        // N_EDGES+1
    int* n_off   = e_off + (N_EDGES + 1);                // N_NODES+1
    int* ebcnt   = n_off + (N_NODES + 1);                // 200 (pad)
    int* nbcnt   = ebcnt + 200;                          // 200
    int* ebOff   = nbcnt + 200;                          // 200
    int* nbOff   = ebOff + 200;                          // 200
    int* ebCur   = nbOff + 200;                          // 200
    int* nbCur   = ebCur + 200;                          // 200
    uintptr_t pa = (uintptr_t)(nbCur + 200);
    pa = (pa + 255) & ~(uintptr_t)255;                   // 256B-align
    __half2* probs_h = (__half2*)pa;                     // N_NODES*64 half2 = 25.6 MB
    unsigned short* probs8 = (unsigned short*)(probs_h + (size_t)N_NODES * 64); // N_NODES*128 fp8 = 12.8 MB
    __half*  edge_feat_h = (__half*)ebkt;                // N_EDGES*K halves (6.4MB), aliases dead ebkt

    hipMemsetAsync(ebcnt, 0, 400 * sizeof(int), stream);

    sm_hist_k<<<SM_BLOCKS + 1024, 256, 0, stream>>>(y, probs_h, probs8,
                                                    node_idx, edge_idx, ebcnt, nbcnt);
    bscan_k<<<1, 512, 0, stream>>>(ebcnt, nbcnt, ebOff, nbOff, ebCur, nbCur, e_off, n_off);
    bpart_k<<<(NNZ + 2047) / 2048, 256, 0, stream>>>(node_idx, edge_idx, ebCur, nbCur, ebkt, nbkt);
    bfill_k<<<NB_E + NB_N, 256, 0, stream>>>(ebkt, nbkt, ebOff, nbOff, e_off, n_off, e_nodes, n_edges);

    mm2_k<<<(N_EDGES + 15) / 16, 256, 0, stream>>>((const unsigned*)probs8, e_off, e_nodes, W, edge_feat_h);
    node_fin_k<<<N_NODES / 16, 256, 0, stream>>>(probs_h, n_off, n_edges, edge_feat_h, out);
}